// Round 3
// baseline (224.252 us; speedup 1.0000x reference)
//
#include <hip/hip_runtime.h>
#include <stdint.h>

// Problem shape (fixed by reference):
#define BATCH 2
#define T_SEQ 2048
#define CDIM  1024
#define NH    16
#define HD    64
#define MROWS (BATCH*T_SEQ)   // 4096

typedef unsigned short u16;
typedef __attribute__((ext_vector_type(8))) short bf16x8;
typedef __attribute__((ext_vector_type(4))) float f32x4;
typedef __attribute__((ext_vector_type(16))) float f32x16;
typedef __attribute__((ext_vector_type(4))) unsigned short u16x4;

__device__ __forceinline__ u16 f2b(float f) {
  union { float f; unsigned int u; } x; x.f = f;
  unsigned int r = x.u + 0x7FFFu + ((x.u >> 16) & 1u);
  return (u16)(r >> 16);
}

__device__ __forceinline__ void gload16(const void* g, void* s) {
  __builtin_amdgcn_global_load_lds(
      (const __attribute__((address_space(1))) void*)g,
      (__attribute__((address_space(3))) void*)s, 16, 0, 0);
}

__device__ __forceinline__ int cvtpk(float lo, float hi_) {
  int w;
  asm("v_cvt_pk_bf16_f32 %0, %1, %2" : "=v"(w) : "v"(lo), "v"(hi_));
  return w;
}

__device__ __forceinline__ bf16x8 mkfrag(int a, int b, int c, int d) {
  union { int i[4]; bf16x8 v; } u;
  u.i[0] = a; u.i[1] = b; u.i[2] = c; u.i[3] = d;
  return u.v;
}

// ---------------- f32 -> bf16 convert (vectorized) ----------------
__global__ __launch_bounds__(256) void cvt4(const float4* __restrict__ in,
                                            u16x4* __restrict__ out, int n4) {
  int i = blockIdx.x * 256 + threadIdx.x;
  if (i < n4) {
    float4 v = in[i];
    u16x4 o = { f2b(v.x), f2b(v.y), f2b(v.z), f2b(v.w) };
    out[i] = o;
  }
}

// ------------- W transpose + convert (4 matrices in one launch) -------------
__global__ __launch_bounds__(256) void w_trans4(const float* __restrict__ W0,
                                                const float* __restrict__ W1,
                                                const float* __restrict__ W2,
                                                const float* __restrict__ W3,
                                                u16* __restrict__ D0,
                                                u16* __restrict__ D3) {
  __shared__ u16 tile[64][72];
  const float* W = (blockIdx.z == 0) ? W0 : (blockIdx.z == 1) ? W1
                 : (blockIdx.z == 2) ? W2 : W3;
  u16* Wt = (blockIdx.z == 3) ? D3 : (D0 + (size_t)blockIdx.z * CDIM * CDIM);
  int k0 = blockIdx.x * 64, n0 = blockIdx.y * 64;
  int tid = threadIdx.x;
  #pragma unroll
  for (int i = 0; i < 16; ++i) {
    int c = i * 256 + tid;
    int kr = c >> 6, nc = c & 63;
    tile[kr][nc] = f2b(W[(size_t)(k0 + kr) * CDIM + n0 + nc]);
  }
  __syncthreads();
  #pragma unroll
  for (int i = 0; i < 16; ++i) {
    int c = i * 256 + tid;
    int nr = c >> 6, kc = c & 63;
    Wt[(size_t)(n0 + nr) * CDIM + k0 + kc] = tile[kc][nr];
  }
}

// ---------------- RoPE cos/sin table ----------------
__global__ __launch_bounds__(256) void rope_tab(float* __restrict__ cosT,
                                                float* __restrict__ sinT) {
  int i = blockIdx.x * 256 + threadIdx.x;   // t*32 + j
  int t = i >> 5, j = i & 31;
  float inv = expf(-(float)j * (9.210340371976184f / 32.0f)); // 10000^(-2j/64)
  float ang = (float)t * inv;
  cosT[i] = cosf(ang);
  sinT[i] = sinf(ang);
}

// ------- QKV GEMM with fused RoPE + head-layout epilogue -------
// C[4096][3072] = xb * Wqkv^T; epilogue rotates q,k pairs (f32), scales q by
// 0.125*log2(e) (softmax uses exp2), writes Qr/Kr [BH][T][64], Vt [BH][64][T].
__global__ __launch_bounds__(256) void gemm_qkv(const u16* __restrict__ A,
                                                const u16* __restrict__ Bt,
                                                const float* __restrict__ cosT,
                                                const float* __restrict__ sinT,
                                                u16* __restrict__ Qr,
                                                u16* __restrict__ Kr,
                                                u16* __restrict__ Vt) {
  __shared__ u16 As[128 * 64];
  __shared__ u16 Bs[128 * 64];
  const int tid = threadIdx.x;
  const int wid = tid >> 6, lane = tid & 63;
  const int wr = wid >> 1, wc = wid & 1;
  const int col = lane & 15, kq = lane >> 4;
  const int arow0 = blockIdx.x * 128, bcol0 = blockIdx.y * 128;

  f32x4 acc[4][4] = {};

  for (int k0 = 0; k0 < CDIM; k0 += 64) {
    #pragma unroll
    for (int it = 0; it < 4; ++it) {
      int c = it * 256 + tid;
      int r = c >> 3, c8 = (c & 7) << 3;
      gload16(A  + (size_t)(arow0 + r) * CDIM + k0 + c8, (char*)As + c * 16);
      gload16(Bt + (size_t)(bcol0 + r) * CDIM + k0 + c8, (char*)Bs + c * 16);
    }
    asm volatile("s_waitcnt vmcnt(0)" ::: "memory");
    __syncthreads();
    #pragma unroll
    for (int kk = 0; kk < 64; kk += 32) {
      bf16x8 a[4], b[4];
      #pragma unroll
      for (int m = 0; m < 4; ++m)
        a[m] = *(const bf16x8*)(As + (wr * 64 + m * 16 + col) * 64 + kk + kq * 8);
      #pragma unroll
      for (int n = 0; n < 4; ++n)
        b[n] = *(const bf16x8*)(Bs + (wc * 64 + n * 16 + col) * 64 + kk + kq * 8);
      #pragma unroll
      for (int m = 0; m < 4; ++m)
        #pragma unroll
        for (int n = 0; n < 4; ++n)
          acc[m][n] = __builtin_amdgcn_mfma_f32_16x16x32_bf16(a[m], b[n], acc[m][n], 0, 0, 0);
    }
    __syncthreads();
  }

  #pragma unroll
  for (int m = 0; m < 4; ++m)
    #pragma unroll
    for (int n = 0; n < 4; ++n) {
      int cc = bcol0 + wc * 64 + n * 16 + col;
      int type = cc >> 10;            // 0=q 1=k 2=v  (wave-uniform)
      int cm = cc & 1023;
      int h = cm >> 6, d = cm & 63;
      int j = d >> 1;
      #pragma unroll
      for (int i = 0; i < 4; ++i) {
        int rr = arow0 + wr * 64 + m * 16 + kq * 4 + i;
        int b = rr >> 11, t = rr & 2047;
        float val = acc[m][n][i];
        float pv = __shfl_xor(val, 1, 64);     // partner (d^1) value
        if (type == 2) {
          Vt[(((size_t)(b * NH + h)) * 64 + d) * T_SEQ + t] = f2b(val);
        } else {
          float c = cosT[t * 32 + j], s = sinT[t * 32 + j];
          float r = (d & 1) ? (val * c + pv * s) : (val * c - pv * s);
          if (type == 0) r *= 0.18033688011112042f;   // 0.125 * log2(e)
          u16* dst = type ? Kr : Qr;
          dst[(((size_t)(b * NH + h)) * T_SEQ + t) * 64 + d] = f2b(r);
        }
      }
    }
}

// ---------------- GEMM (O-proj): C = A * Bt^T + bias, f32 out ----------------
__global__ __launch_bounds__(256) void gemm_bt(const u16* __restrict__ A,
                                               const u16* __restrict__ Bt,
                                               float* __restrict__ C,
                                               const float* __restrict__ bias,
                                               int K, int ldc) {
  __shared__ u16 As[128 * 64];
  __shared__ u16 Bs[128 * 64];
  const int tid = threadIdx.x;
  const int wid = tid >> 6, lane = tid & 63;
  const int wr = wid >> 1, wc = wid & 1;
  const int col = lane & 15, kq = lane >> 4;
  const int arow0 = blockIdx.x * 128, bcol0 = blockIdx.y * 128;

  f32x4 acc[4][4] = {};

  for (int k0 = 0; k0 < K; k0 += 64) {
    #pragma unroll
    for (int it = 0; it < 4; ++it) {
      int c = it * 256 + tid;
      int r = c >> 3, c8 = (c & 7) << 3;
      gload16(A  + (size_t)(arow0 + r) * K + k0 + c8, (char*)As + c * 16);
      gload16(Bt + (size_t)(bcol0 + r) * K + k0 + c8, (char*)Bs + c * 16);
    }
    asm volatile("s_waitcnt vmcnt(0)" ::: "memory");
    __syncthreads();
    #pragma unroll
    for (int kk = 0; kk < 64; kk += 32) {
      bf16x8 a[4], b[4];
      #pragma unroll
      for (int m = 0; m < 4; ++m)
        a[m] = *(const bf16x8*)(As + (wr * 64 + m * 16 + col) * 64 + kk + kq * 8);
      #pragma unroll
      for (int n = 0; n < 4; ++n)
        b[n] = *(const bf16x8*)(Bs + (wc * 64 + n * 16 + col) * 64 + kk + kq * 8);
      #pragma unroll
      for (int m = 0; m < 4; ++m)
        #pragma unroll
        for (int n = 0; n < 4; ++n)
          acc[m][n] = __builtin_amdgcn_mfma_f32_16x16x32_bf16(a[m], b[n], acc[m][n], 0, 0, 0);
    }
    __syncthreads();
  }

  #pragma unroll
  for (int m = 0; m < 4; ++m)
    #pragma unroll
    for (int n = 0; n < 4; ++n) {
      int cc = bcol0 + wc * 64 + n * 16 + col;
      float bv = bias ? bias[cc] : 0.0f;
      #pragma unroll
      for (int i = 0; i < 4; ++i) {
        int rr = arow0 + wr * 64 + m * 16 + kq * 4 + i;
        C[(size_t)rr * ldc + cc] = acc[m][n][i] + bv;
      }
    }
}

// ---------------- Flash attention v3: no-LDS, barrier-free, 1 wave/block ------
// Swapped-operand 32x32 MFMA; K/V fragments read directly from L2-resident
// global memory; K prefetched one tile ahead. 32 q-rows per wave.
__global__ __launch_bounds__(64) void attn_fwd3(const u16* __restrict__ Q,
                                                const u16* __restrict__ K,
                                                const u16* __restrict__ V,   // [BH][64][T]
                                                u16* __restrict__ O) {       // [B*T][1024]
  __shared__ __align__(16) char smem[4608];

  // XCD-grouped swizzle: XCD x serves bh in {4x..4x+3}; longest q first.
  const int s_ = blockIdx.x;            // 0..63
  const int g  = blockIdx.y;            // 0..31
  const int bh = ((s_ & 7) << 2) | (g & 3);
  const int qc = 63 - (((s_ >> 3) << 3) | (g >> 2));   // 0..63
  const int b = bh >> 4, h = bh & 15;
  const int lane = threadIdx.x & 63;
  const int l31 = lane & 31, hi = lane >> 5;
  const int wq0 = qc * 32;
  const int qrow = wq0 + l31;

  // Q fragments (B-operand): qa[dk] = Q[q=l31][d = 16*dk + 8*hi + j]
  bf16x8 qa[4];
  const u16* qbase = Q + ((size_t)bh * T_SEQ + qrow) * 64 + hi * 8;
  #pragma unroll
  for (int dk = 0; dk < 4; ++dk)
    qa[dk] = *(const bf16x8*)(qbase + dk * 16);

  const u16* kb = K + (size_t)bh * T_SEQ * 64;
  const u16* vb = V + (size_t)bh * 64 * T_SEQ;
  const int rk = l31 * 64 + hi * 8;            // K-tile lane offset (elements)
  const int rv = l31 * T_SEQ + hi * 8;         // V-tile lane offset

  float M = -1e30f, L = 0.f;
  f32x16 ot0 = {}, ot1 = {};

  const int nkt = ((wq0 + 31) >> 6) + 1;

  // preload K tile 0 fragments (A-operand): ka[hf*4+dk] = K[kv0+l31+32hf][16dk+8hi+j]
  bf16x8 ka[8];
  #pragma unroll
  for (int hf = 0; hf < 2; ++hf)
    #pragma unroll
    for (int dk = 0; dk < 4; ++dk)
      ka[hf * 4 + dk] = *(const bf16x8*)(kb + rk + hf * 2048 + dk * 16);

  for (int kt = 0; kt < nkt; ++kt) {
    const int kv0 = kt * 64;

    // issue V loads for this tile early (consumed after softmax)
    bf16x8 va[8];
    #pragma unroll
    for (int hf = 0; hf < 2; ++hf)
      #pragma unroll
      for (int ks = 0; ks < 4; ++ks)
        va[hf * 4 + ks] = *(const bf16x8*)(vb + rv + hf * 32 * T_SEQ + kv0 + ks * 16);

    // ---- S^T = K . Q^T ----
    f32x16 st0 = {}, st1 = {};
    #pragma unroll
    for (int dk = 0; dk < 4; ++dk) {
      st0 = __builtin_amdgcn_mfma_f32_32x32x16_bf16(ka[dk],     qa[dk], st0, 0, 0, 0);
      st1 = __builtin_amdgcn_mfma_f32_32x32x16_bf16(ka[4 + dk], qa[dk], st1, 0, 0, 0);
    }

    // prefetch next K tile (latency hidden under softmax + PV)
    if (kt + 1 < nkt) {
      const u16* kbn = kb + (size_t)(kv0 + 64) * 64;
      #pragma unroll
      for (int hf = 0; hf < 2; ++hf)
        #pragma unroll
        for (int dk = 0; dk < 4; ++dk)
          ka[hf * 4 + dk] = *(const bf16x8*)(kbn + rk + hf * 2048 + dk * 16);
    }

    // ---- causal mask (diagonal tile only) ----
    if (kt == nkt - 1) {
      #pragma unroll
      for (int r = 0; r < 16; ++r) {
        int kl = (r & 3) + 8 * (r >> 2) + 4 * hi;
        if (kv0 + kl > qrow)      st0[r] = -1e30f;
        if (kv0 + 32 + kl > qrow) st1[r] = -1e30f;
      }
    }

    // ---- online softmax (lane-local rows; scores already in log2 domain) ----
    float t0 = fmaxf(st0[0], st1[0]), t1 = fmaxf(st0[1], st1[1]);
    float t2 = fmaxf(st0[2], st1[2]), t3 = fmaxf(st0[3], st1[3]);
    #pragma unroll
    for (int r = 4; r < 16; r += 4) {
      t0 = fmaxf(t0, fmaxf(st0[r],     st1[r]));
      t1 = fmaxf(t1, fmaxf(st0[r + 1], st1[r + 1]));
      t2 = fmaxf(t2, fmaxf(st0[r + 2], st1[r + 2]));
      t3 = fmaxf(t3, fmaxf(st0[r + 3], st1[r + 3]));
    }
    float mx = fmaxf(fmaxf(t0, t1), fmaxf(t2, t3));
    mx = fmaxf(mx, __shfl_xor(mx, 32, 64));
    float Mn = fmaxf(M, mx);
    float corr = exp2f(M - Mn);
    M = Mn;

    float s0 = 0.f, s1 = 0.f, s2 = 0.f, s3 = 0.f;
    #pragma unroll
    for (int r = 0; r < 16; r += 4) {
      st0[r]     = exp2f(st0[r]     - M); st1[r]     = exp2f(st1[r]     - M);
      st0[r + 1] = exp2f(st0[r + 1] - M); st1[r + 1] = exp2f(st1[r + 1] - M);
      st0[r + 2] = exp2f(st0[r + 2] - M); st1[r + 2] = exp2f(st1[r + 2] - M);
      st0[r + 3] = exp2f(st0[r + 3] - M); st1[r + 3] = exp2f(st1[r + 3] - M);
      s0 += st0[r]     + st1[r];
      s1 += st0[r + 1] + st1[r + 1];
      s2 += st0[r + 2] + st1[r + 2];
      s3 += st0[r + 3] + st1[r + 3];
    }
    float sum = (s0 + s1) + (s2 + s3);
    sum += __shfl_xor(sum, 32, 64);
    L = L * corr + sum;
    ot0 *= corr;
    ot1 *= corr;

    // ---- P^T -> bf16 B-fragments via cvt_pk + permlane32_swap ----
    int x0 = cvtpk(st0[0], st0[1]),   y0 = cvtpk(st0[4], st0[5]);
    int x1 = cvtpk(st0[2], st0[3]),   y1 = cvtpk(st0[6], st0[7]);
    int x2 = cvtpk(st0[8], st0[9]),   y2 = cvtpk(st0[12], st0[13]);
    int x3 = cvtpk(st0[10], st0[11]), y3 = cvtpk(st0[14], st0[15]);
    asm("v_permlane32_swap_b32 %0, %1" : "+v"(x0), "+v"(y0));
    asm("v_permlane32_swap_b32 %0, %1" : "+v"(x1), "+v"(y1));
    asm("v_permlane32_swap_b32 %0, %1" : "+v"(x2), "+v"(y2));
    asm("v_permlane32_swap_b32 %0, %1" : "+v"(x3), "+v"(y3));
    int z0 = cvtpk(st1[0], st1[1]),   w0 = cvtpk(st1[4], st1[5]);
    int z1 = cvtpk(st1[2], st1[3]),   w1 = cvtpk(st1[6], st1[7]);
    int z2 = cvtpk(st1[8], st1[9]),   w2 = cvtpk(st1[12], st1[13]);
    int z3 = cvtpk(st1[10], st1[11]), w3 = cvtpk(st1[14], st1[15]);
    asm("v_permlane32_swap_b32 %0, %1" : "+v"(z0), "+v"(w0));
    asm("v_permlane32_swap_b32 %0, %1" : "+v"(z1), "+v"(w1));
    asm("v_permlane32_swap_b32 %0, %1" : "+v"(z2), "+v"(w2));
    asm("v_permlane32_swap_b32 %0, %1" : "+v"(z3), "+v"(w3));
    bf16x8 pb[4];
    pb[0] = mkfrag(x0, x1, y0, y1);   // k  0..15
    pb[1] = mkfrag(x2, x3, y2, y3);   // k 16..31
    pb[2] = mkfrag(z0, z1, w0, w1);   // k 32..47
    pb[3] = mkfrag(z2, z3, w2, w3);   // k 48..63

    // ---- O^T += V^T . P^T ----
    #pragma unroll
    for (int ks = 0; ks < 4; ++ks) {
      ot0 = __builtin_amdgcn_mfma_f32_32x32x16_bf16(va[ks],     pb[ks], ot0, 0, 0, 0);
      ot1 = __builtin_amdgcn_mfma_f32_32x32x16_bf16(va[4 + ks], pb[ks], ot1, 0, 0, 0);
    }
  }

  // ---- epilogue: transpose O^T -> O via LDS, coalesced store ----
  char* ep = smem;                    // [32 q][72 d] u16, row stride 144B
  float invL = 1.0f / L;
  #pragma unroll
  for (int r = 0; r < 16; r += 2) {
    int d0_ = (r & 3) + 8 * (r >> 2) + 4 * hi;   // even
    int wA = cvtpk(ot0[r] * invL, ot0[r + 1] * invL);
    *(int*)(ep + l31 * 144 + d0_ * 2) = wA;
    int wB = cvtpk(ot1[r] * invL, ot1[r + 1] * invL);
    *(int*)(ep + l31 * 144 + (32 + d0_) * 2) = wB;
  }
  asm volatile("s_waitcnt lgkmcnt(0)" ::: "memory");
  #pragma unroll
  for (int pass = 0; pass < 4; ++pass) {
    int qr = pass * 8 + (lane >> 3);
    bf16x8 val = *(const bf16x8*)(ep + qr * 144 + (lane & 7) * 16);
    int t = wq0 + qr;
    *(bf16x8*)(O + ((size_t)(b * T_SEQ + t)) * 1024 + h * 64 + (lane & 7) * 8) = val;
  }
}

// ---------------- host launch ----------------
extern "C" void kernel_launch(void* const* d_in, const int* in_sizes, int n_in,
                              void* d_out, int out_size, void* d_ws, size_t ws_size,
                              hipStream_t stream) {
  (void)in_sizes; (void)n_in; (void)out_size; (void)ws_size;
  const float* x  = (const float*)d_in[0];
  const float* Wq = (const float*)d_in[1];
  const float* Wk = (const float*)d_in[2];
  const float* Wv = (const float*)d_in[3];
  const float* Wo = (const float*)d_in[4];
  const float* bo = (const float*)d_in[5];
  float* out = (float*)d_out;

  char* ws = (char*)d_ws;
  u16*   xb   = (u16*)(ws);                         //  8 MB
  u16*   Wqkv = (u16*)(ws + (size_t)( 8u << 20));   //  6 MB  [3072][1024] bf16
  u16*   Wot  = (u16*)(ws + (size_t)(14u << 20));   //  2 MB
  u16*   Qr   = (u16*)(ws + (size_t)(16u << 20));   //  8 MB  [BH][T][64]
  u16*   Kr   = (u16*)(ws + (size_t)(24u << 20));   //  8 MB
  u16*   Vt   = (u16*)(ws + (size_t)(32u << 20));   //  8 MB  [BH][64][T]
  u16*   Ob   = (u16*)(ws + (size_t)(40u << 20));   //  8 MB  [4096][1024]
  float* cosT = (float*)(ws + (size_t)(48u << 20)); // 256 KB
  float* sinT = (float*)(ws + (size_t)(48u << 20) + (1u << 18));

  cvt4<<<dim3(MROWS * CDIM / 4 / 256), dim3(256), 0, stream>>>(
      (const float4*)x, (u16x4*)xb, MROWS * CDIM / 4);
  w_trans4<<<dim3(16, 16, 4), dim3(256), 0, stream>>>(Wq, Wk, Wv, Wo, Wqkv, Wot);
  rope_tab<<<dim3(T_SEQ * 32 / 256), dim3(256), 0, stream>>>(cosT, sinT);

  // fused QKV projection + RoPE + head layout
  gemm_qkv<<<dim3(32, 24), dim3(256), 0, stream>>>(xb, Wqkv, cosT, sinT, Qr, Kr, Vt);

  // attention (barrier-free, L2-direct)
  attn_fwd3<<<dim3(64, 32), dim3(64), 0, stream>>>(Qr, Kr, Vt, Ob);

  // output projection + bias -> f32 out
  gemm_bt<<<dim3(32, 8), dim3(256), 0, stream>>>(Ob, Wot, out, bo, CDIM, CDIM);
}

// Round 4
// 169.505 us; speedup vs baseline: 1.3230x; 1.3230x over previous
//
#include <hip/hip_runtime.h>
#include <stdint.h>

// Problem shape (fixed by reference):
#define BATCH 2
#define T_SEQ 2048
#define CDIM  1024
#define NH    16
#define HD    64
#define MROWS (BATCH*T_SEQ)   // 4096

typedef unsigned short u16;
typedef __attribute__((ext_vector_type(8))) short bf16x8;
typedef __attribute__((ext_vector_type(4))) float f32x4;
typedef __attribute__((ext_vector_type(16))) float f32x16;
typedef __attribute__((ext_vector_type(4))) unsigned short u16x4;

__device__ __forceinline__ u16 f2b(float f) {
  union { float f; unsigned int u; } x; x.f = f;
  unsigned int r = x.u + 0x7FFFu + ((x.u >> 16) & 1u);
  return (u16)(r >> 16);
}

__device__ __forceinline__ void gload16(const void* g, void* s) {
  __builtin_amdgcn_global_load_lds(
      (const __attribute__((address_space(1))) void*)g,
      (__attribute__((address_space(3))) void*)s, 16, 0, 0);
}

__device__ __forceinline__ int cvtpk(float lo, float hi_) {
  int w;
  asm("v_cvt_pk_bf16_f32 %0, %1, %2" : "=v"(w) : "v"(lo), "v"(hi_));
  return w;
}

__device__ __forceinline__ bf16x8 mkfrag(int a, int b, int c, int d) {
  union { int i[4]; bf16x8 v; } u;
  u.i[0] = a; u.i[1] = b; u.i[2] = c; u.i[3] = d;
  return u.v;
}

// ---------------- f32 -> bf16 convert (vectorized) ----------------
__global__ __launch_bounds__(256) void cvt4(const float4* __restrict__ in,
                                            u16x4* __restrict__ out, int n4) {
  int i = blockIdx.x * 256 + threadIdx.x;
  if (i < n4) {
    float4 v = in[i];
    u16x4 o = { f2b(v.x), f2b(v.y), f2b(v.z), f2b(v.w) };
    out[i] = o;
  }
}

// ------------- W transpose + convert (4 matrices in one launch) -------------
__global__ __launch_bounds__(256) void w_trans4(const float* __restrict__ W0,
                                                const float* __restrict__ W1,
                                                const float* __restrict__ W2,
                                                const float* __restrict__ W3,
                                                u16* __restrict__ D0,
                                                u16* __restrict__ D3) {
  __shared__ u16 tile[64][72];
  const float* W = (blockIdx.z == 0) ? W0 : (blockIdx.z == 1) ? W1
                 : (blockIdx.z == 2) ? W2 : W3;
  u16* Wt = (blockIdx.z == 3) ? D3 : (D0 + (size_t)blockIdx.z * CDIM * CDIM);
  int k0 = blockIdx.x * 64, n0 = blockIdx.y * 64;
  int tid = threadIdx.x;
  #pragma unroll
  for (int i = 0; i < 16; ++i) {
    int c = i * 256 + tid;
    int kr = c >> 6, nc = c & 63;
    tile[kr][nc] = f2b(W[(size_t)(k0 + kr) * CDIM + n0 + nc]);
  }
  __syncthreads();
  #pragma unroll
  for (int i = 0; i < 16; ++i) {
    int c = i * 256 + tid;
    int nr = c >> 6, kc = c & 63;
    Wt[(size_t)(n0 + nr) * CDIM + k0 + kc] = tile[kc][nr];
  }
}

// ---------------- RoPE cos/sin table ----------------
__global__ __launch_bounds__(256) void rope_tab(float* __restrict__ cosT,
                                                float* __restrict__ sinT) {
  int i = blockIdx.x * 256 + threadIdx.x;   // t*32 + j
  int t = i >> 5, j = i & 31;
  float inv = expf(-(float)j * (9.210340371976184f / 32.0f)); // 10000^(-2j/64)
  float ang = (float)t * inv;
  cosT[i] = cosf(ang);
  sinT[i] = sinf(ang);
}

// ------- QKV GEMM with fused RoPE + head-layout epilogue -------
__global__ __launch_bounds__(256) void gemm_qkv(const u16* __restrict__ A,
                                                const u16* __restrict__ Bt,
                                                const float* __restrict__ cosT,
                                                const float* __restrict__ sinT,
                                                u16* __restrict__ Qr,
                                                u16* __restrict__ Kr,
                                                u16* __restrict__ Vt) {
  __shared__ u16 As[128 * 64];
  __shared__ u16 Bs[128 * 64];
  const int tid = threadIdx.x;
  const int wid = tid >> 6, lane = tid & 63;
  const int wr = wid >> 1, wc = wid & 1;
  const int col = lane & 15, kq = lane >> 4;
  const int arow0 = blockIdx.x * 128, bcol0 = blockIdx.y * 128;

  f32x4 acc[4][4] = {};

  for (int k0 = 0; k0 < CDIM; k0 += 64) {
    #pragma unroll
    for (int it = 0; it < 4; ++it) {
      int c = it * 256 + tid;
      int r = c >> 3, c8 = (c & 7) << 3;
      gload16(A  + (size_t)(arow0 + r) * CDIM + k0 + c8, (char*)As + c * 16);
      gload16(Bt + (size_t)(bcol0 + r) * CDIM + k0 + c8, (char*)Bs + c * 16);
    }
    asm volatile("s_waitcnt vmcnt(0)" ::: "memory");
    __syncthreads();
    #pragma unroll
    for (int kk = 0; kk < 64; kk += 32) {
      bf16x8 a[4], b[4];
      #pragma unroll
      for (int m = 0; m < 4; ++m)
        a[m] = *(const bf16x8*)(As + (wr * 64 + m * 16 + col) * 64 + kk + kq * 8);
      #pragma unroll
      for (int n = 0; n < 4; ++n)
        b[n] = *(const bf16x8*)(Bs + (wc * 64 + n * 16 + col) * 64 + kk + kq * 8);
      #pragma unroll
      for (int m = 0; m < 4; ++m)
        #pragma unroll
        for (int n = 0; n < 4; ++n)
          acc[m][n] = __builtin_amdgcn_mfma_f32_16x16x32_bf16(a[m], b[n], acc[m][n], 0, 0, 0);
    }
    __syncthreads();
  }

  #pragma unroll
  for (int m = 0; m < 4; ++m)
    #pragma unroll
    for (int n = 0; n < 4; ++n) {
      int cc = bcol0 + wc * 64 + n * 16 + col;
      int type = cc >> 10;            // 0=q 1=k 2=v  (wave-uniform)
      int cm = cc & 1023;
      int h = cm >> 6, d = cm & 63;
      int j = d >> 1;
      #pragma unroll
      for (int i = 0; i < 4; ++i) {
        int rr = arow0 + wr * 64 + m * 16 + kq * 4 + i;
        int b = rr >> 11, t = rr & 2047;
        float val = acc[m][n][i];
        float pv = __shfl_xor(val, 1, 64);     // partner (d^1) value
        if (type == 2) {
          Vt[(((size_t)(b * NH + h)) * 64 + d) * T_SEQ + t] = f2b(val);
        } else {
          float c = cosT[t * 32 + j], s = sinT[t * 32 + j];
          float r = (d & 1) ? (val * c + pv * s) : (val * c - pv * s);
          if (type == 0) r *= 0.18033688011112042f;   // 0.125 * log2(e)
          u16* dst = type ? Kr : Qr;
          dst[(((size_t)(b * NH + h)) * T_SEQ + t) * 64 + d] = f2b(r);
        }
      }
    }
}

// ---------------- GEMM (O-proj): C = A * Bt^T + bias, f32 out ----------------
__global__ __launch_bounds__(256) void gemm_bt(const u16* __restrict__ A,
                                               const u16* __restrict__ Bt,
                                               float* __restrict__ C,
                                               const float* __restrict__ bias,
                                               int K, int ldc) {
  __shared__ u16 As[128 * 64];
  __shared__ u16 Bs[128 * 64];
  const int tid = threadIdx.x;
  const int wid = tid >> 6, lane = tid & 63;
  const int wr = wid >> 1, wc = wid & 1;
  const int col = lane & 15, kq = lane >> 4;
  const int arow0 = blockIdx.x * 128, bcol0 = blockIdx.y * 128;

  f32x4 acc[4][4] = {};

  for (int k0 = 0; k0 < K; k0 += 64) {
    #pragma unroll
    for (int it = 0; it < 4; ++it) {
      int c = it * 256 + tid;
      int r = c >> 3, c8 = (c & 7) << 3;
      gload16(A  + (size_t)(arow0 + r) * K + k0 + c8, (char*)As + c * 16);
      gload16(Bt + (size_t)(bcol0 + r) * K + k0 + c8, (char*)Bs + c * 16);
    }
    asm volatile("s_waitcnt vmcnt(0)" ::: "memory");
    __syncthreads();
    #pragma unroll
    for (int kk = 0; kk < 64; kk += 32) {
      bf16x8 a[4], b[4];
      #pragma unroll
      for (int m = 0; m < 4; ++m)
        a[m] = *(const bf16x8*)(As + (wr * 64 + m * 16 + col) * 64 + kk + kq * 8);
      #pragma unroll
      for (int n = 0; n < 4; ++n)
        b[n] = *(const bf16x8*)(Bs + (wc * 64 + n * 16 + col) * 64 + kk + kq * 8);
      #pragma unroll
      for (int m = 0; m < 4; ++m)
        #pragma unroll
        for (int n = 0; n < 4; ++n)
          acc[m][n] = __builtin_amdgcn_mfma_f32_16x16x32_bf16(a[m], b[n], acc[m][n], 0, 0, 0);
    }
    __syncthreads();
  }

  #pragma unroll
  for (int m = 0; m < 4; ++m)
    #pragma unroll
    for (int n = 0; n < 4; ++n) {
      int cc = bcol0 + wc * 64 + n * 16 + col;
      float bv = bias ? bias[cc] : 0.0f;
      #pragma unroll
      for (int i = 0; i < 4; ++i) {
        int rr = arow0 + wr * 64 + m * 16 + kq * 4 + i;
        C[(size_t)rr * ldc + cc] = acc[m][n][i] + bv;
      }
    }
}

// ---------------- Flash attention v4: 4 waves, dbuf gload_lds, counted vmcnt --
// Swapped-operand 32x32 MFMA; K/V staged in XOR-swizzled LDS via pre-swizzled
// global source (linear gload_lds dest); 2-phase pipeline, raw barriers.
__global__ __launch_bounds__(256, 4) void attn_fwd4(const u16* __restrict__ Q,
                                                    const u16* __restrict__ K,
                                                    const u16* __restrict__ V,  // [BH][64][T]
                                                    u16* __restrict__ O) {      // [B*T][1024]
  __shared__ __align__(16) char smem[32768];  // 2 x (K 8KB + V 8KB); epilogue overlays

  const int bh = blockIdx.x;                  // XCD = bh&7 -> 4 heads per XCD L2
  const int s_ = blockIdx.y;                  // 0..15
  const int qc = (s_ & 1) ? ((s_ - 1) >> 1) : (15 - (s_ >> 1));  // 15,0,14,1,...
  const int q0 = qc * 128;
  const int b = bh >> 4, h = bh & 15;
  const int tid = threadIdx.x;
  const int wid = tid >> 6, lane = tid & 63;
  const int l31 = lane & 31, hi = lane >> 5;
  const int wq0 = q0 + wid * 32;
  const int qrow = wq0 + l31;
  const int nkt = (q0 + 128) >> 6;            // 2*(qc+1) tiles

  // Q fragments (B-operand): qa[dk] = Q[q=l31][d = 16*dk + 8*hi + j]
  bf16x8 qa[4];
  const u16* qbase = Q + ((size_t)bh * T_SEQ + qrow) * 64 + hi * 8;
  #pragma unroll
  for (int dk = 0; dk < 4; ++dk)
    qa[dk] = *(const bf16x8*)(qbase + dk * 16);

  const u16* kb = K + (size_t)bh * T_SEQ * 64;
  const u16* vb = V + (size_t)bh * 64 * T_SEQ;

  // staging: 4 gload16/thread/tile; LDS linear, global source pre-swizzled
  auto STAGE = [&](int kv0, int bsel) {
    char* dstK = smem + bsel * 16384;
    char* dstV = dstK + 8192;
    #pragma unroll
    for (int i = 0; i < 2; ++i) {
      int idx = i * 256 + tid;
      int r = idx >> 3, c = idx & 7;
      int cs = (c ^ (r & 7)) << 3;           // involution: matches read-side XOR
      gload16(kb + (size_t)(kv0 + r) * 64 + cs, dstK + idx * 16);
      gload16(vb + (size_t)r * T_SEQ + kv0 + cs, dstV + idx * 16);
    }
  };

  float M = -1e30f, L = 0.f;
  f32x16 ot0 = {}, ot1 = {};

  STAGE(0, 0);                                // prologue

  for (int kt = 0; kt < nkt; ++kt) {
    const int kv0 = kt << 6;
    const int cur = kt & 1;
    if (kt + 1 < nkt) {
      STAGE((kt + 1) << 6, cur ^ 1);
      asm volatile("s_waitcnt vmcnt(4)" ::: "memory");  // tile kt done, kt+1 in flight
    } else {
      asm volatile("s_waitcnt vmcnt(0)" ::: "memory");
    }
    __builtin_amdgcn_s_barrier();

    if (kv0 <= wq0 + 31) {                    // wave-uniform activity test
      const char* Ks = smem + cur * 16384;
      const char* Vs = Ks + 8192;

      // ---- S^T = K . Q^T ----
      f32x16 st0 = {}, st1 = {};
      __builtin_amdgcn_s_setprio(1);
      #pragma unroll
      for (int dk = 0; dk < 4; ++dk) {
        int ch = dk * 2 + hi;
        bf16x8 ka0 = *(const bf16x8*)(Ks + l31 * 128 + (((ch ^ (l31 & 7))) << 4));
        bf16x8 ka1 = *(const bf16x8*)(Ks + (l31 + 32) * 128 + ((ch ^ (l31 & 7)) << 4));
        st0 = __builtin_amdgcn_mfma_f32_32x32x16_bf16(ka0, qa[dk], st0, 0, 0, 0);
        st1 = __builtin_amdgcn_mfma_f32_32x32x16_bf16(ka1, qa[dk], st1, 0, 0, 0);
      }
      __builtin_amdgcn_s_setprio(0);

      // ---- causal mask (diagonal region only) ----
      if (kv0 + 63 > wq0) {
        #pragma unroll
        for (int r = 0; r < 16; ++r) {
          int kl = (r & 3) + 8 * (r >> 2) + 4 * hi;
          if (kv0 + kl > qrow)      st0[r] = -1e30f;
          if (kv0 + 32 + kl > qrow) st1[r] = -1e30f;
        }
      }

      // ---- online softmax (lane-local rows; log2 domain) ----
      float t0 = fmaxf(st0[0], st1[0]), t1 = fmaxf(st0[1], st1[1]);
      float t2 = fmaxf(st0[2], st1[2]), t3 = fmaxf(st0[3], st1[3]);
      #pragma unroll
      for (int r = 4; r < 16; r += 4) {
        t0 = fmaxf(t0, fmaxf(st0[r],     st1[r]));
        t1 = fmaxf(t1, fmaxf(st0[r + 1], st1[r + 1]));
        t2 = fmaxf(t2, fmaxf(st0[r + 2], st1[r + 2]));
        t3 = fmaxf(t3, fmaxf(st0[r + 3], st1[r + 3]));
      }
      float mx = fmaxf(fmaxf(t0, t1), fmaxf(t2, t3));
      mx = fmaxf(mx, __shfl_xor(mx, 32, 64));
      float Mn = fmaxf(M, mx);
      float corr = exp2f(M - Mn);
      M = Mn;

      float s0 = 0.f, s1 = 0.f, s2 = 0.f, s3 = 0.f;
      #pragma unroll
      for (int r = 0; r < 16; r += 4) {
        st0[r]     = exp2f(st0[r]     - M); st1[r]     = exp2f(st1[r]     - M);
        st0[r + 1] = exp2f(st0[r + 1] - M); st1[r + 1] = exp2f(st1[r + 1] - M);
        st0[r + 2] = exp2f(st0[r + 2] - M); st1[r + 2] = exp2f(st1[r + 2] - M);
        st0[r + 3] = exp2f(st0[r + 3] - M); st1[r + 3] = exp2f(st1[r + 3] - M);
        s0 += st0[r]     + st1[r];
        s1 += st0[r + 1] + st1[r + 1];
        s2 += st0[r + 2] + st1[r + 2];
        s3 += st0[r + 3] + st1[r + 3];
      }
      float sum = (s0 + s1) + (s2 + s3);
      sum += __shfl_xor(sum, 32, 64);
      L = L * corr + sum;
      ot0 *= corr;
      ot1 *= corr;

      // ---- P^T -> bf16 B-fragments via cvt_pk + permlane32_swap ----
      int x0 = cvtpk(st0[0], st0[1]),   y0 = cvtpk(st0[4], st0[5]);
      int x1 = cvtpk(st0[2], st0[3]),   y1 = cvtpk(st0[6], st0[7]);
      int x2 = cvtpk(st0[8], st0[9]),   y2 = cvtpk(st0[12], st0[13]);
      int x3 = cvtpk(st0[10], st0[11]), y3 = cvtpk(st0[14], st0[15]);
      asm("v_permlane32_swap_b32 %0, %1" : "+v"(x0), "+v"(y0));
      asm("v_permlane32_swap_b32 %0, %1" : "+v"(x1), "+v"(y1));
      asm("v_permlane32_swap_b32 %0, %1" : "+v"(x2), "+v"(y2));
      asm("v_permlane32_swap_b32 %0, %1" : "+v"(x3), "+v"(y3));
      int z0 = cvtpk(st1[0], st1[1]),   w0 = cvtpk(st1[4], st1[5]);
      int z1 = cvtpk(st1[2], st1[3]),   w1 = cvtpk(st1[6], st1[7]);
      int z2 = cvtpk(st1[8], st1[9]),   w2 = cvtpk(st1[12], st1[13]);
      int z3 = cvtpk(st1[10], st1[11]), w3 = cvtpk(st1[14], st1[15]);
      asm("v_permlane32_swap_b32 %0, %1" : "+v"(z0), "+v"(w0));
      asm("v_permlane32_swap_b32 %0, %1" : "+v"(z1), "+v"(w1));
      asm("v_permlane32_swap_b32 %0, %1" : "+v"(z2), "+v"(w2));
      asm("v_permlane32_swap_b32 %0, %1" : "+v"(z3), "+v"(w3));
      bf16x8 pb[4];
      pb[0] = mkfrag(x0, x1, y0, y1);   // k  0..15
      pb[1] = mkfrag(x2, x3, y2, y3);   // k 16..31
      pb[2] = mkfrag(z0, z1, w0, w1);   // k 32..47
      pb[3] = mkfrag(z2, z3, w2, w3);   // k 48..63

      // ---- O^T += V^T . P^T ----
      __builtin_amdgcn_s_setprio(1);
      #pragma unroll
      for (int ks = 0; ks < 4; ++ks) {
        int ch = ks * 2 + hi;
        bf16x8 va0 = *(const bf16x8*)(Vs + l31 * 128 + ((ch ^ (l31 & 7)) << 4));
        bf16x8 va1 = *(const bf16x8*)(Vs + (l31 + 32) * 128 + ((ch ^ (l31 & 7)) << 4));
        ot0 = __builtin_amdgcn_mfma_f32_32x32x16_bf16(va0, pb[ks], ot0, 0, 0, 0);
        ot1 = __builtin_amdgcn_mfma_f32_32x32x16_bf16(va1, pb[ks], ot1, 0, 0, 0);
      }
      __builtin_amdgcn_s_setprio(0);
    }

    asm volatile("s_waitcnt lgkmcnt(0)" ::: "memory");
    __builtin_amdgcn_s_barrier();             // buf[cur] free for overwrite
  }

  // ---- epilogue: transpose O^T -> O via per-wave LDS region, coalesced store --
  char* ep = smem + wid * 4608;               // [32 q][72 d] u16, row stride 144B
  float invL = 1.0f / L;
  #pragma unroll
  for (int r = 0; r < 16; r += 2) {
    int d0_ = (r & 3) + 8 * (r >> 2) + 4 * hi;   // even
    int wA = cvtpk(ot0[r] * invL, ot0[r + 1] * invL);
    *(int*)(ep + l31 * 144 + d0_ * 2) = wA;
    int wB = cvtpk(ot1[r] * invL, ot1[r + 1] * invL);
    *(int*)(ep + l31 * 144 + (32 + d0_) * 2) = wB;
  }
  asm volatile("s_waitcnt lgkmcnt(0)" ::: "memory");
  #pragma unroll
  for (int pass = 0; pass < 4; ++pass) {
    int qr = pass * 8 + (lane >> 3);
    bf16x8 val = *(const bf16x8*)(ep + qr * 144 + (lane & 7) * 16);
    int t = wq0 + qr;
    *(bf16x8*)(O + ((size_t)(b * T_SEQ + t)) * 1024 + h * 64 + (lane & 7) * 8) = val;
  }
}

// ---------------- host launch ----------------
extern "C" void kernel_launch(void* const* d_in, const int* in_sizes, int n_in,
                              void* d_out, int out_size, void* d_ws, size_t ws_size,
                              hipStream_t stream) {
  (void)in_sizes; (void)n_in; (void)out_size; (void)ws_size;
  const float* x  = (const float*)d_in[0];
  const float* Wq = (const float*)d_in[1];
  const float* Wk = (const float*)d_in[2];
  const float* Wv = (const float*)d_in[3];
  const float* Wo = (const float*)d_in[4];
  const float* bo = (const float*)d_in[5];
  float* out = (float*)d_out;

  char* ws = (char*)d_ws;
  u16*   xb   = (u16*)(ws);                         //  8 MB
  u16*   Wqkv = (u16*)(ws + (size_t)( 8u << 20));   //  6 MB  [3072][1024] bf16
  u16*   Wot  = (u16*)(ws + (size_t)(14u << 20));   //  2 MB
  u16*   Qr   = (u16*)(ws + (size_t)(16u << 20));   //  8 MB  [BH][T][64]
  u16*   Kr   = (u16*)(ws + (size_t)(24u << 20));   //  8 MB
  u16*   Vt   = (u16*)(ws + (size_t)(32u << 20));   //  8 MB  [BH][64][T]
  u16*   Ob   = (u16*)(ws + (size_t)(40u << 20));   //  8 MB  [4096][1024]
  float* cosT = (float*)(ws + (size_t)(48u << 20)); // 256 KB
  float* sinT = (float*)(ws + (size_t)(48u << 20) + (1u << 18));

  cvt4<<<dim3(MROWS * CDIM / 4 / 256), dim3(256), 0, stream>>>(
      (const float4*)x, (u16x4*)xb, MROWS * CDIM / 4);
  w_trans4<<<dim3(16, 16, 4), dim3(256), 0, stream>>>(Wq, Wk, Wv, Wo, Wqkv, Wot);
  rope_tab<<<dim3(T_SEQ * 32 / 256), dim3(256), 0, stream>>>(cosT, sinT);

  // fused QKV projection + RoPE + head layout
  gemm_qkv<<<dim3(32, 24), dim3(256), 0, stream>>>(xb, Wqkv, cosT, sinT, Qr, Kr, Vt);

  // attention (dbuf LDS, counted vmcnt)
  attn_fwd4<<<dim3(32, 16), dim3(256), 0, stream>>>(Qr, Kr, Vt, Ob);

  // output projection + bias -> f32 out
  gemm_bt<<<dim3(32, 8), dim3(256), 0, stream>>>(Ob, Wot, out, bo, CDIM, CDIM);
}

// Round 5
// 148.966 us; speedup vs baseline: 1.5054x; 1.1379x over previous
//
#include <hip/hip_runtime.h>
#include <stdint.h>

// Problem shape (fixed by reference):
#define BATCH 2
#define T_SEQ 2048
#define CDIM  1024
#define NH    16
#define HD    64
#define MROWS (BATCH*T_SEQ)   // 4096

typedef unsigned short u16;
typedef __attribute__((ext_vector_type(8))) short bf16x8;
typedef __attribute__((ext_vector_type(4))) float f32x4;
typedef __attribute__((ext_vector_type(16))) float f32x16;
typedef __attribute__((ext_vector_type(4))) unsigned short u16x4;

__device__ __forceinline__ u16 f2b(float f) {
  union { float f; unsigned int u; } x; x.f = f;
  unsigned int r = x.u + 0x7FFFu + ((x.u >> 16) & 1u);
  return (u16)(r >> 16);
}

__device__ __forceinline__ void gload16(const void* g, void* s) {
  __builtin_amdgcn_global_load_lds(
      (const __attribute__((address_space(1))) void*)g,
      (__attribute__((address_space(3))) void*)s, 16, 0, 0);
}

__device__ __forceinline__ int cvtpk(float lo, float hi_) {
  int w;
  asm("v_cvt_pk_bf16_f32 %0, %1, %2" : "=v"(w) : "v"(lo), "v"(hi_));
  return w;
}

__device__ __forceinline__ bf16x8 mkfrag(int a, int b, int c, int d) {
  union { int i[4]; bf16x8 v; } u;
  u.i[0] = a; u.i[1] = b; u.i[2] = c; u.i[3] = d;
  return u.v;
}

// ---------------- f32 -> bf16 convert (vectorized) ----------------
__global__ __launch_bounds__(256) void cvt4(const float4* __restrict__ in,
                                            u16x4* __restrict__ out, int n4) {
  int i = blockIdx.x * 256 + threadIdx.x;
  if (i < n4) {
    float4 v = in[i];
    u16x4 o = { f2b(v.x), f2b(v.y), f2b(v.z), f2b(v.w) };
    out[i] = o;
  }
}

// ------------- W transpose + convert (4 matrices in one launch) -------------
__global__ __launch_bounds__(256) void w_trans4(const float* __restrict__ W0,
                                                const float* __restrict__ W1,
                                                const float* __restrict__ W2,
                                                const float* __restrict__ W3,
                                                u16* __restrict__ D0,
                                                u16* __restrict__ D3) {
  __shared__ u16 tile[64][72];
  const float* W = (blockIdx.z == 0) ? W0 : (blockIdx.z == 1) ? W1
                 : (blockIdx.z == 2) ? W2 : W3;
  u16* Wt = (blockIdx.z == 3) ? D3 : (D0 + (size_t)blockIdx.z * CDIM * CDIM);
  int k0 = blockIdx.x * 64, n0 = blockIdx.y * 64;
  int tid = threadIdx.x;
  #pragma unroll
  for (int i = 0; i < 16; ++i) {
    int c = i * 256 + tid;
    int kr = c >> 6, nc = c & 63;
    tile[kr][nc] = f2b(W[(size_t)(k0 + kr) * CDIM + n0 + nc]);
  }
  __syncthreads();
  #pragma unroll
  for (int i = 0; i < 16; ++i) {
    int c = i * 256 + tid;
    int nr = c >> 6, kc = c & 63;
    Wt[(size_t)(n0 + nr) * CDIM + k0 + kc] = tile[kc][nr];
  }
}

// ---------------- RoPE cos/sin table ----------------
__global__ __launch_bounds__(256) void rope_tab(float* __restrict__ cosT,
                                                float* __restrict__ sinT) {
  int i = blockIdx.x * 256 + threadIdx.x;   // t*32 + j
  int t = i >> 5, j = i & 31;
  float inv = expf(-(float)j * (9.210340371976184f / 32.0f)); // 10000^(-2j/64)
  float ang = (float)t * inv;
  cosT[i] = cosf(ang);
  sinT[i] = sinf(ang);
}

// ------- QKV GEMM (256x256 tile, 8 waves, dbuf + counted-prefetch) -------
// C[4096][3072] = xb * Wqkv^T; epilogue rotates q,k pairs (f32), scales q by
// 0.125*log2(e), writes Qr/Kr [BH][T][64], Vt [BH][64][T].
__global__ __launch_bounds__(512, 2) void gemm_qkv256(const u16* __restrict__ A,
                                                      const u16* __restrict__ Bt,
                                                      const float* __restrict__ cosT,
                                                      const float* __restrict__ sinT,
                                                      u16* __restrict__ Qr,
                                                      u16* __restrict__ Kr,
                                                      u16* __restrict__ Vt) {
  __shared__ __align__(16) char smem[131072];   // 2 x (A 32KB + B 32KB)
  const int tid = threadIdx.x;
  const int wid = tid >> 6, lane = tid & 63;
  const int wm = wid >> 2, wn = wid & 3;        // 2 x 4 waves
  const int col = lane & 15, kq = lane >> 4;
  // bijective XCD swizzle (192 blocks, 192%8==0): same-XCD blocks share B-panels
  const int swz = (blockIdx.x & 7) * 24 + (blockIdx.x >> 3);
  const int arow0 = (swz & 15) * 256, bcol0 = (swz >> 4) * 256;

  // stage one K-step tile (A[256][64] + B[256][64]) with pre-swizzled source
  auto STAGE = [&](int k0, int bsel) {
    char* dA = smem + bsel * 65536;
    char* dB = dA + 32768;
    #pragma unroll
    for (int i = 0; i < 4; ++i) {
      int idx = i * 512 + tid;                  // 0..2047 chunks
      int r = idx >> 3, p = idx & 7;
      int src = (p ^ (r & 7)) << 3;             // involution matches read XOR
      gload16(A  + (size_t)(arow0 + r) * CDIM + k0 + src, dA + idx * 16);
      gload16(Bt + (size_t)(bcol0 + r) * CDIM + k0 + src, dB + idx * 16);
    }
  };

  f32x4 acc[8][4] = {};

  STAGE(0, 0);
  for (int kt = 0; kt < 16; ++kt) {
    asm volatile("s_waitcnt vmcnt(0)" ::: "memory");   // tile kt landed (full-iter cover)
    __builtin_amdgcn_s_barrier();
    if (kt < 15) STAGE((kt + 1) * 64, (kt + 1) & 1);   // in flight across compute+barrier
    const char* As_ = smem + (kt & 1) * 65536;
    const char* Bs_ = As_ + 32768;
    #pragma unroll
    for (int q = 0; q < 4; ++q) {               // quadrant phases
      const int qm = q >> 1, qn = q & 1;
      bf16x8 a[4][2], b[2][2];
      #pragma unroll
      for (int m = 0; m < 4; ++m)
        #pragma unroll
        for (int ks = 0; ks < 2; ++ks) {
          int row = wm * 128 + qm * 64 + m * 16 + col;
          int ch = ks * 4 + kq;
          a[m][ks] = *(const bf16x8*)(As_ + row * 128 + ((ch ^ (row & 7)) << 4));
        }
      #pragma unroll
      for (int n = 0; n < 2; ++n)
        #pragma unroll
        for (int ks = 0; ks < 2; ++ks) {
          int rowb = wn * 64 + qn * 32 + n * 16 + col;
          int ch = ks * 4 + kq;
          b[n][ks] = *(const bf16x8*)(Bs_ + rowb * 128 + ((ch ^ (rowb & 7)) << 4));
        }
      __builtin_amdgcn_s_setprio(1);
      #pragma unroll
      for (int m = 0; m < 4; ++m)
        #pragma unroll
        for (int n = 0; n < 2; ++n)
          #pragma unroll
          for (int ks = 0; ks < 2; ++ks)
            acc[qm * 4 + m][qn * 2 + n] = __builtin_amdgcn_mfma_f32_16x16x32_bf16(
                a[m][ks], b[n][ks], acc[qm * 4 + m][qn * 2 + n], 0, 0, 0);
      __builtin_amdgcn_s_setprio(0);
    }
  }

  // ---- epilogue: RoPE + head layout ----
  #pragma unroll
  for (int im = 0; im < 8; ++im)
    #pragma unroll
    for (int in = 0; in < 4; ++in) {
      int cc = bcol0 + wn * 64 + in * 16 + col;
      int type = cc >> 10;            // 0=q 1=k 2=v
      int cm = cc & 1023;
      int h = cm >> 6, d = cm & 63;
      int j = d >> 1;
      #pragma unroll
      for (int i = 0; i < 4; ++i) {
        int rr = arow0 + wm * 128 + im * 16 + kq * 4 + i;
        int b = rr >> 11, t = rr & 2047;
        float val = acc[im][in][i];
        float pv = __shfl_xor(val, 1, 64);     // partner (d^1) value
        if (type == 2) {
          Vt[(((size_t)(b * NH + h)) * 64 + d) * T_SEQ + t] = f2b(val);
        } else {
          float c = cosT[t * 32 + j], s = sinT[t * 32 + j];
          float r = (d & 1) ? (val * c + pv * s) : (val * c - pv * s);
          if (type == 0) r *= 0.18033688011112042f;   // 0.125 * log2(e)
          u16* dst = type ? Kr : Qr;
          dst[(((size_t)(b * NH + h)) * T_SEQ + t) * 64 + d] = f2b(r);
        }
      }
    }
}

// ------- O-proj GEMM (128x128, dbuf + counted-prefetch + swizzle): f32 out -----
__global__ __launch_bounds__(256, 2) void gemm_bt(const u16* __restrict__ A,
                                                  const u16* __restrict__ Bt,
                                                  float* __restrict__ C,
                                                  const float* __restrict__ bias,
                                                  int K, int ldc) {
  __shared__ __align__(16) char smem[65536];    // 2 x (A 16KB + B 16KB)
  const int tid = threadIdx.x;
  const int wid = tid >> 6, lane = tid & 63;
  const int wr = wid >> 1, wc = wid & 1;
  const int col = lane & 15, kq = lane >> 4;
  const int swz = (blockIdx.x & 7) * 32 + (blockIdx.x >> 3);   // 256 blocks
  const int arow0 = (swz & 31) * 128, bcol0 = (swz >> 5) * 128;
  const int NT = K >> 6;

  auto STAGE = [&](int k0, int bsel) {
    char* dA = smem + bsel * 32768;
    char* dB = dA + 16384;
    #pragma unroll
    for (int i = 0; i < 4; ++i) {
      int idx = i * 256 + tid;                  // 0..1023 chunks
      int r = idx >> 3, p = idx & 7;
      int src = (p ^ (r & 7)) << 3;
      gload16(A  + (size_t)(arow0 + r) * K + k0 + src, dA + idx * 16);
      gload16(Bt + (size_t)(bcol0 + r) * K + k0 + src, dB + idx * 16);
    }
  };

  f32x4 acc[4][4] = {};

  STAGE(0, 0);
  for (int kt = 0; kt < NT; ++kt) {
    asm volatile("s_waitcnt vmcnt(0)" ::: "memory");
    __builtin_amdgcn_s_barrier();
    if (kt + 1 < NT) STAGE((kt + 1) * 64, (kt + 1) & 1);
    const char* As_ = smem + (kt & 1) * 32768;
    const char* Bs_ = As_ + 16384;
    bf16x8 a[4][2], b[4][2];
    #pragma unroll
    for (int m = 0; m < 4; ++m)
      #pragma unroll
      for (int ks = 0; ks < 2; ++ks) {
        int row = wr * 64 + m * 16 + col;
        int ch = ks * 4 + kq;
        a[m][ks] = *(const bf16x8*)(As_ + row * 128 + ((ch ^ (row & 7)) << 4));
      }
    #pragma unroll
    for (int n = 0; n < 4; ++n)
      #pragma unroll
      for (int ks = 0; ks < 2; ++ks) {
        int rowb = wc * 64 + n * 16 + col;
        int ch = ks * 4 + kq;
        b[n][ks] = *(const bf16x8*)(Bs_ + rowb * 128 + ((ch ^ (rowb & 7)) << 4));
      }
    __builtin_amdgcn_s_setprio(1);
    #pragma unroll
    for (int m = 0; m < 4; ++m)
      #pragma unroll
      for (int n = 0; n < 4; ++n)
        #pragma unroll
        for (int ks = 0; ks < 2; ++ks)
          acc[m][n] = __builtin_amdgcn_mfma_f32_16x16x32_bf16(a[m][ks], b[n][ks],
                                                              acc[m][n], 0, 0, 0);
    __builtin_amdgcn_s_setprio(0);
  }

  #pragma unroll
  for (int m = 0; m < 4; ++m)
    #pragma unroll
    for (int n = 0; n < 4; ++n) {
      int cc = bcol0 + wc * 64 + n * 16 + col;
      float bv = bias ? bias[cc] : 0.0f;
      #pragma unroll
      for (int i = 0; i < 4; ++i) {
        int rr = arow0 + wr * 64 + m * 16 + kq * 4 + i;
        C[(size_t)rr * ldc + cc] = acc[m][n][i] + bv;
      }
    }
}

// ---------------- Flash attention v4: 4 waves, dbuf gload_lds, counted vmcnt --
__global__ __launch_bounds__(256, 4) void attn_fwd4(const u16* __restrict__ Q,
                                                    const u16* __restrict__ K,
                                                    const u16* __restrict__ V,  // [BH][64][T]
                                                    u16* __restrict__ O) {      // [B*T][1024]
  __shared__ __align__(16) char smem[32768];  // 2 x (K 8KB + V 8KB); epilogue overlays

  const int bh = blockIdx.x;                  // XCD = bh&7 -> 4 heads per XCD L2
  const int s_ = blockIdx.y;                  // 0..15
  const int qc = (s_ & 1) ? ((s_ - 1) >> 1) : (15 - (s_ >> 1));  // 15,0,14,1,...
  const int q0 = qc * 128;
  const int b = bh >> 4, h = bh & 15;
  const int tid = threadIdx.x;
  const int wid = tid >> 6, lane = tid & 63;
  const int l31 = lane & 31, hi = lane >> 5;
  const int wq0 = q0 + wid * 32;
  const int qrow = wq0 + l31;
  const int nkt = (q0 + 128) >> 6;            // 2*(qc+1) tiles

  bf16x8 qa[4];
  const u16* qbase = Q + ((size_t)bh * T_SEQ + qrow) * 64 + hi * 8;
  #pragma unroll
  for (int dk = 0; dk < 4; ++dk)
    qa[dk] = *(const bf16x8*)(qbase + dk * 16);

  const u16* kb = K + (size_t)bh * T_SEQ * 64;
  const u16* vb = V + (size_t)bh * 64 * T_SEQ;

  auto STAGE = [&](int kv0, int bsel) {
    char* dstK = smem + bsel * 16384;
    char* dstV = dstK + 8192;
    #pragma unroll
    for (int i = 0; i < 2; ++i) {
      int idx = i * 256 + tid;
      int r = idx >> 3, c = idx & 7;
      int cs = (c ^ (r & 7)) << 3;
      gload16(kb + (size_t)(kv0 + r) * 64 + cs, dstK + idx * 16);
      gload16(vb + (size_t)r * T_SEQ + kv0 + cs, dstV + idx * 16);
    }
  };

  float M = -1e30f, L = 0.f;
  f32x16 ot0 = {}, ot1 = {};

  STAGE(0, 0);

  for (int kt = 0; kt < nkt; ++kt) {
    const int kv0 = kt << 6;
    const int cur = kt & 1;
    if (kt + 1 < nkt) {
      STAGE((kt + 1) << 6, cur ^ 1);
      asm volatile("s_waitcnt vmcnt(4)" ::: "memory");
    } else {
      asm volatile("s_waitcnt vmcnt(0)" ::: "memory");
    }
    __builtin_amdgcn_s_barrier();

    if (kv0 <= wq0 + 31) {
      const char* Ks = smem + cur * 16384;
      const char* Vs = Ks + 8192;

      f32x16 st0 = {}, st1 = {};
      __builtin_amdgcn_s_setprio(1);
      #pragma unroll
      for (int dk = 0; dk < 4; ++dk) {
        int ch = dk * 2 + hi;
        bf16x8 ka0 = *(const bf16x8*)(Ks + l31 * 128 + (((ch ^ (l31 & 7))) << 4));
        bf16x8 ka1 = *(const bf16x8*)(Ks + (l31 + 32) * 128 + ((ch ^ (l31 & 7)) << 4));
        st0 = __builtin_amdgcn_mfma_f32_32x32x16_bf16(ka0, qa[dk], st0, 0, 0, 0);
        st1 = __builtin_amdgcn_mfma_f32_32x32x16_bf16(ka1, qa[dk], st1, 0, 0, 0);
      }
      __builtin_amdgcn_s_setprio(0);

      if (kv0 + 63 > wq0) {
        #pragma unroll
        for (int r = 0; r < 16; ++r) {
          int kl = (r & 3) + 8 * (r >> 2) + 4 * hi;
          if (kv0 + kl > qrow)      st0[r] = -1e30f;
          if (kv0 + 32 + kl > qrow) st1[r] = -1e30f;
        }
      }

      float t0 = fmaxf(st0[0], st1[0]), t1 = fmaxf(st0[1], st1[1]);
      float t2 = fmaxf(st0[2], st1[2]), t3 = fmaxf(st0[3], st1[3]);
      #pragma unroll
      for (int r = 4; r < 16; r += 4) {
        t0 = fmaxf(t0, fmaxf(st0[r],     st1[r]));
        t1 = fmaxf(t1, fmaxf(st0[r + 1], st1[r + 1]));
        t2 = fmaxf(t2, fmaxf(st0[r + 2], st1[r + 2]));
        t3 = fmaxf(t3, fmaxf(st0[r + 3], st1[r + 3]));
      }
      float mx = fmaxf(fmaxf(t0, t1), fmaxf(t2, t3));
      mx = fmaxf(mx, __shfl_xor(mx, 32, 64));
      float Mn = fmaxf(M, mx);
      float corr = exp2f(M - Mn);
      M = Mn;

      float s0 = 0.f, s1 = 0.f, s2 = 0.f, s3 = 0.f;
      #pragma unroll
      for (int r = 0; r < 16; r += 4) {
        st0[r]     = exp2f(st0[r]     - M); st1[r]     = exp2f(st1[r]     - M);
        st0[r + 1] = exp2f(st0[r + 1] - M); st1[r + 1] = exp2f(st1[r + 1] - M);
        st0[r + 2] = exp2f(st0[r + 2] - M); st1[r + 2] = exp2f(st1[r + 2] - M);
        st0[r + 3] = exp2f(st0[r + 3] - M); st1[r + 3] = exp2f(st1[r + 3] - M);
        s0 += st0[r]     + st1[r];
        s1 += st0[r + 1] + st1[r + 1];
        s2 += st0[r + 2] + st1[r + 2];
        s3 += st0[r + 3] + st1[r + 3];
      }
      float sum = (s0 + s1) + (s2 + s3);
      sum += __shfl_xor(sum, 32, 64);
      L = L * corr + sum;
      ot0 *= corr;
      ot1 *= corr;

      int x0 = cvtpk(st0[0], st0[1]),   y0 = cvtpk(st0[4], st0[5]);
      int x1 = cvtpk(st0[2], st0[3]),   y1 = cvtpk(st0[6], st0[7]);
      int x2 = cvtpk(st0[8], st0[9]),   y2 = cvtpk(st0[12], st0[13]);
      int x3 = cvtpk(st0[10], st0[11]), y3 = cvtpk(st0[14], st0[15]);
      asm("v_permlane32_swap_b32 %0, %1" : "+v"(x0), "+v"(y0));
      asm("v_permlane32_swap_b32 %0, %1" : "+v"(x1), "+v"(y1));
      asm("v_permlane32_swap_b32 %0, %1" : "+v"(x2), "+v"(y2));
      asm("v_permlane32_swap_b32 %0, %1" : "+v"(x3), "+v"(y3));
      int z0 = cvtpk(st1[0], st1[1]),   w0 = cvtpk(st1[4], st1[5]);
      int z1 = cvtpk(st1[2], st1[3]),   w1 = cvtpk(st1[6], st1[7]);
      int z2 = cvtpk(st1[8], st1[9]),   w2 = cvtpk(st1[12], st1[13]);
      int z3 = cvtpk(st1[10], st1[11]), w3 = cvtpk(st1[14], st1[15]);
      asm("v_permlane32_swap_b32 %0, %1" : "+v"(z0), "+v"(w0));
      asm("v_permlane32_swap_b32 %0, %1" : "+v"(z1), "+v"(w1));
      asm("v_permlane32_swap_b32 %0, %1" : "+v"(z2), "+v"(w2));
      asm("v_permlane32_swap_b32 %0, %1" : "+v"(z3), "+v"(w3));
      bf16x8 pb[4];
      pb[0] = mkfrag(x0, x1, y0, y1);
      pb[1] = mkfrag(x2, x3, y2, y3);
      pb[2] = mkfrag(z0, z1, w0, w1);
      pb[3] = mkfrag(z2, z3, w2, w3);

      __builtin_amdgcn_s_setprio(1);
      #pragma unroll
      for (int ks = 0; ks < 4; ++ks) {
        int ch = ks * 2 + hi;
        bf16x8 va0 = *(const bf16x8*)(Vs + l31 * 128 + ((ch ^ (l31 & 7)) << 4));
        bf16x8 va1 = *(const bf16x8*)(Vs + (l31 + 32) * 128 + ((ch ^ (l31 & 7)) << 4));
        ot0 = __builtin_amdgcn_mfma_f32_32x32x16_bf16(va0, pb[ks], ot0, 0, 0, 0);
        ot1 = __builtin_amdgcn_mfma_f32_32x32x16_bf16(va1, pb[ks], ot1, 0, 0, 0);
      }
      __builtin_amdgcn_s_setprio(0);
    }

    asm volatile("s_waitcnt lgkmcnt(0)" ::: "memory");
    __builtin_amdgcn_s_barrier();
  }

  char* ep = smem + wid * 4608;
  float invL = 1.0f / L;
  #pragma unroll
  for (int r = 0; r < 16; r += 2) {
    int d0_ = (r & 3) + 8 * (r >> 2) + 4 * hi;
    int wA = cvtpk(ot0[r] * invL, ot0[r + 1] * invL);
    *(int*)(ep + l31 * 144 + d0_ * 2) = wA;
    int wB = cvtpk(ot1[r] * invL, ot1[r + 1] * invL);
    *(int*)(ep + l31 * 144 + (32 + d0_) * 2) = wB;
  }
  asm volatile("s_waitcnt lgkmcnt(0)" ::: "memory");
  #pragma unroll
  for (int pass = 0; pass < 4; ++pass) {
    int qr = pass * 8 + (lane >> 3);
    bf16x8 val = *(const bf16x8*)(ep + qr * 144 + (lane & 7) * 16);
    int t = wq0 + qr;
    *(bf16x8*)(O + ((size_t)(b * T_SEQ + t)) * 1024 + h * 64 + (lane & 7) * 8) = val;
  }
}

// ---------------- host launch ----------------
extern "C" void kernel_launch(void* const* d_in, const int* in_sizes, int n_in,
                              void* d_out, int out_size, void* d_ws, size_t ws_size,
                              hipStream_t stream) {
  (void)in_sizes; (void)n_in; (void)out_size; (void)ws_size;
  const float* x  = (const float*)d_in[0];
  const float* Wq = (const float*)d_in[1];
  const float* Wk = (const float*)d_in[2];
  const float* Wv = (const float*)d_in[3];
  const float* Wo = (const float*)d_in[4];
  const float* bo = (const float*)d_in[5];
  float* out = (float*)d_out;

  char* ws = (char*)d_ws;
  u16*   xb   = (u16*)(ws);                         //  8 MB
  u16*   Wqkv = (u16*)(ws + (size_t)( 8u << 20));   //  6 MB  [3072][1024] bf16
  u16*   Wot  = (u16*)(ws + (size_t)(14u << 20));   //  2 MB
  u16*   Qr   = (u16*)(ws + (size_t)(16u << 20));   //  8 MB  [BH][T][64]
  u16*   Kr   = (u16*)(ws + (size_t)(24u << 20));   //  8 MB
  u16*   Vt   = (u16*)(ws + (size_t)(32u << 20));   //  8 MB  [BH][64][T]
  u16*   Ob   = (u16*)(ws + (size_t)(40u << 20));   //  8 MB  [4096][1024]
  float* cosT = (float*)(ws + (size_t)(48u << 20)); // 256 KB
  float* sinT = (float*)(ws + (size_t)(48u << 20) + (1u << 18));

  cvt4<<<dim3(MROWS * CDIM / 4 / 256), dim3(256), 0, stream>>>(
      (const float4*)x, (u16x4*)xb, MROWS * CDIM / 4);
  w_trans4<<<dim3(16, 16, 4), dim3(256), 0, stream>>>(Wq, Wk, Wv, Wo, Wqkv, Wot);
  rope_tab<<<dim3(T_SEQ * 32 / 256), dim3(256), 0, stream>>>(cosT, sinT);

  // fused QKV projection + RoPE + head layout (256^2 tile, 8 waves)
  gemm_qkv256<<<dim3(192), dim3(512), 0, stream>>>(xb, Wqkv, cosT, sinT, Qr, Kr, Vt);

  // attention (dbuf LDS, counted vmcnt)
  attn_fwd4<<<dim3(32, 16), dim3(256), 0, stream>>>(Qr, Kr, Vt, Ob);

  // output projection + bias -> f32 out
  gemm_bt<<<dim3(256), dim3(256), 0, stream>>>(Ob, Wot, out, bo, CDIM, CDIM);
}

// Round 6
// 139.258 us; speedup vs baseline: 1.6103x; 1.0697x over previous
//
#include <hip/hip_runtime.h>
#include <stdint.h>

// Problem shape (fixed by reference):
#define BATCH 2
#define T_SEQ 2048
#define CDIM  1024
#define NH    16
#define HD    64
#define MROWS (BATCH*T_SEQ)   // 4096

typedef unsigned short u16;
typedef __attribute__((ext_vector_type(8))) short bf16x8;
typedef __attribute__((ext_vector_type(4))) float f32x4;
typedef __attribute__((ext_vector_type(16))) float f32x16;
typedef __attribute__((ext_vector_type(4))) unsigned short u16x4;

__device__ __forceinline__ u16 f2b(float f) {
  union { float f; unsigned int u; } x; x.f = f;
  unsigned int r = x.u + 0x7FFFu + ((x.u >> 16) & 1u);
  return (u16)(r >> 16);
}

__device__ __forceinline__ void gload16(const void* g, void* s) {
  __builtin_amdgcn_global_load_lds(
      (const __attribute__((address_space(1))) void*)g,
      (__attribute__((address_space(3))) void*)s, 16, 0, 0);
}

__device__ __forceinline__ int cvtpk(float lo, float hi_) {
  int w;
  asm("v_cvt_pk_bf16_f32 %0, %1, %2" : "=v"(w) : "v"(lo), "v"(hi_));
  return w;
}

__device__ __forceinline__ bf16x8 mkfrag(int a, int b, int c, int d) {
  union { int i[4]; bf16x8 v; } u;
  u.i[0] = a; u.i[1] = b; u.i[2] = c; u.i[3] = d;
  return u.v;
}

// ---------------- f32 -> bf16 convert (vectorized) ----------------
__global__ __launch_bounds__(256) void cvt4(const float4* __restrict__ in,
                                            u16x4* __restrict__ out, int n4) {
  int i = blockIdx.x * 256 + threadIdx.x;
  if (i < n4) {
    float4 v = in[i];
    u16x4 o = { f2b(v.x), f2b(v.y), f2b(v.z), f2b(v.w) };
    out[i] = o;
  }
}

// ------------- W transpose + convert (4 matrices in one launch) -------------
__global__ __launch_bounds__(256) void w_trans4(const float* __restrict__ W0,
                                                const float* __restrict__ W1,
                                                const float* __restrict__ W2,
                                                const float* __restrict__ W3,
                                                u16* __restrict__ D0,
                                                u16* __restrict__ D3) {
  __shared__ u16 tile[64][72];
  const float* W = (blockIdx.z == 0) ? W0 : (blockIdx.z == 1) ? W1
                 : (blockIdx.z == 2) ? W2 : W3;
  u16* Wt = (blockIdx.z == 3) ? D3 : (D0 + (size_t)blockIdx.z * CDIM * CDIM);
  int k0 = blockIdx.x * 64, n0 = blockIdx.y * 64;
  int tid = threadIdx.x;
  #pragma unroll
  for (int i = 0; i < 16; ++i) {
    int c = i * 256 + tid;
    int kr = c >> 6, nc = c & 63;
    tile[kr][nc] = f2b(W[(size_t)(k0 + kr) * CDIM + n0 + nc]);
  }
  __syncthreads();
  #pragma unroll
  for (int i = 0; i < 16; ++i) {
    int c = i * 256 + tid;
    int nr = c >> 6, kc = c & 63;
    Wt[(size_t)(n0 + nr) * CDIM + k0 + kc] = tile[kc][nr];
  }
}

// ---------------- RoPE cos/sin table ----------------
__global__ __launch_bounds__(256) void rope_tab(float* __restrict__ cosT,
                                                float* __restrict__ sinT) {
  int i = blockIdx.x * 256 + threadIdx.x;   // t*32 + j
  int t = i >> 5, j = i & 31;
  float inv = expf(-(float)j * (9.210340371976184f / 32.0f)); // 10000^(-2j/64)
  float ang = (float)t * inv;
  cosT[i] = cosf(ang);
  sinT[i] = sinf(ang);
}

// ------- QKV GEMM (256x192 tile, 8 waves, dbuf, counted vmcnt, 1-read frags) ---
// C[4096][3072] = xb * Wqkv^T; epilogue rotates q,k pairs (f32), scales q by
// 0.125*log2(e), writes Qr/Kr [BH][T][64], Vt [BH][64][T].
// Grid: 256 blocks = exactly 1/CU; XCD x owns B-panels {2x,2x+1} (L2 locality).
__global__ __launch_bounds__(512, 2) void gemm_qkv256(const u16* __restrict__ A,
                                                      const u16* __restrict__ Bt,
                                                      const float* __restrict__ cosT,
                                                      const float* __restrict__ sinT,
                                                      u16* __restrict__ Qr,
                                                      u16* __restrict__ Kr,
                                                      u16* __restrict__ Vt) {
  __shared__ __align__(16) char smem[114688];   // 2 x (A 32KB + B 24KB)
  const int tid = threadIdx.x;
  const int wid = tid >> 6, lane = tid & 63;
  const int wm = wid >> 2, wn = wid & 3;        // 2 x 4 waves; wave out = 128x48
  const int col = lane & 15, kq = lane >> 4;
  const int xcd = blockIdx.x & 7, bi = blockIdx.x >> 3;
  const int arow0 = (bi & 15) * 256;
  const int bcol0 = (xcd * 2 + (bi >> 4)) * 192;

  // stage one K-step tile (A[256][64] 4 chunks/thread + B[192][64] 3 chunks/thread)
  auto STAGE = [&](int k0, int bsel) {
    char* dA = smem + bsel * 57344;
    char* dB = dA + 32768;
    #pragma unroll
    for (int i = 0; i < 4; ++i) {
      int idx = i * 512 + tid;                  // 0..2047
      int r = idx >> 3, p = idx & 7;
      int src = (p ^ (r & 7)) << 3;             // involution matches read XOR
      gload16(A + (size_t)(arow0 + r) * CDIM + k0 + src, dA + idx * 16);
    }
    #pragma unroll
    for (int i = 0; i < 3; ++i) {
      int idx = i * 512 + tid;                  // 0..1535
      int r = idx >> 3, p = idx & 7;
      int src = (p ^ (r & 7)) << 3;
      gload16(Bt + (size_t)(bcol0 + r) * CDIM + k0 + src, dB + idx * 16);
    }
  };

  f32x4 acc[8][3] = {};

  STAGE(0, 0);
  for (int kt = 0; kt < 16; ++kt) {
    if (kt < 15) {
      STAGE((kt + 1) * 64, (kt + 1) & 1);       // 7 loads in flight across compute
      asm volatile("s_waitcnt vmcnt(7)" ::: "memory");   // tile kt landed
    } else {
      asm volatile("s_waitcnt vmcnt(0)" ::: "memory");
    }
    __builtin_amdgcn_s_barrier();

    const char* As_ = smem + (kt & 1) * 57344;
    const char* Bs_ = As_ + 32768;

    // each fragment read exactly once per K-step (22 ds_read_b128/wave)
    bf16x8 bfr[3][2], a0[4][2], a1[4][2];
    #pragma unroll
    for (int n = 0; n < 3; ++n)
      #pragma unroll
      for (int ks = 0; ks < 2; ++ks) {
        int rowb = wn * 48 + n * 16 + col;
        bfr[n][ks] = *(const bf16x8*)(Bs_ + rowb * 128 + (((ks * 4 + kq) ^ (rowb & 7)) << 4));
      }
    #pragma unroll
    for (int m = 0; m < 4; ++m)
      #pragma unroll
      for (int ks = 0; ks < 2; ++ks) {
        int row = wm * 128 + m * 16 + col;
        a0[m][ks] = *(const bf16x8*)(As_ + row * 128 + (((ks * 4 + kq) ^ (row & 7)) << 4));
        int row1 = row + 64;
        a1[m][ks] = *(const bf16x8*)(As_ + row1 * 128 + (((ks * 4 + kq) ^ (row1 & 7)) << 4));
      }

    __builtin_amdgcn_s_setprio(1);
    #pragma unroll
    for (int m = 0; m < 4; ++m)
      #pragma unroll
      for (int n = 0; n < 3; ++n)
        #pragma unroll
        for (int ks = 0; ks < 2; ++ks)
          acc[m][n] = __builtin_amdgcn_mfma_f32_16x16x32_bf16(a0[m][ks], bfr[n][ks],
                                                              acc[m][n], 0, 0, 0);
    #pragma unroll
    for (int m = 0; m < 4; ++m)
      #pragma unroll
      for (int n = 0; n < 3; ++n)
        #pragma unroll
        for (int ks = 0; ks < 2; ++ks)
          acc[4 + m][n] = __builtin_amdgcn_mfma_f32_16x16x32_bf16(a1[m][ks], bfr[n][ks],
                                                                  acc[4 + m][n], 0, 0, 0);
    __builtin_amdgcn_s_setprio(0);
    __builtin_amdgcn_s_barrier();               // buf[kt&1] free for overwrite
  }

  // ---- epilogue: RoPE + head layout ----
  #pragma unroll
  for (int im = 0; im < 8; ++im)
    #pragma unroll
    for (int in = 0; in < 3; ++in) {
      int cc = bcol0 + wn * 48 + in * 16 + col;
      int type = cc >> 10;            // 0=q 1=k 2=v (uniform within 16-col fragment)
      int cm = cc & 1023;
      int h = cm >> 6, d = cm & 63;
      int j = d >> 1;
      #pragma unroll
      for (int i = 0; i < 4; ++i) {
        int rr = arow0 + wm * 128 + im * 16 + kq * 4 + i;
        int b = rr >> 11, t = rr & 2047;
        float val = acc[im][in][i];
        float pv = __shfl_xor(val, 1, 64);     // partner (d^1) value
        if (type == 2) {
          Vt[(((size_t)(b * NH + h)) * 64 + d) * T_SEQ + t] = f2b(val);
        } else {
          float c = cosT[t * 32 + j], s = sinT[t * 32 + j];
          float r = (d & 1) ? (val * c + pv * s) : (val * c - pv * s);
          if (type == 0) r *= 0.18033688011112042f;   // 0.125 * log2(e)
          u16* dst = type ? Kr : Qr;
          dst[(((size_t)(b * NH + h)) * T_SEQ + t) * 64 + d] = f2b(r);
        }
      }
    }
}

// ------- O-proj GEMM (128x128, dbuf + swizzle): f32 out -----
__global__ __launch_bounds__(256, 2) void gemm_bt(const u16* __restrict__ A,
                                                  const u16* __restrict__ Bt,
                                                  float* __restrict__ C,
                                                  const float* __restrict__ bias,
                                                  int K, int ldc) {
  __shared__ __align__(16) char smem[65536];    // 2 x (A 16KB + B 16KB)
  const int tid = threadIdx.x;
  const int wid = tid >> 6, lane = tid & 63;
  const int wr = wid >> 1, wc = wid & 1;
  const int col = lane & 15, kq = lane >> 4;
  const int swz = (blockIdx.x & 7) * 32 + (blockIdx.x >> 3);   // 256 blocks
  const int arow0 = (swz & 31) * 128, bcol0 = (swz >> 5) * 128;
  const int NT = K >> 6;

  auto STAGE = [&](int k0, int bsel) {
    char* dA = smem + bsel * 32768;
    char* dB = dA + 16384;
    #pragma unroll
    for (int i = 0; i < 4; ++i) {
      int idx = i * 256 + tid;                  // 0..1023 chunks
      int r = idx >> 3, p = idx & 7;
      int src = (p ^ (r & 7)) << 3;
      gload16(A  + (size_t)(arow0 + r) * K + k0 + src, dA + idx * 16);
      gload16(Bt + (size_t)(bcol0 + r) * K + k0 + src, dB + idx * 16);
    }
  };

  f32x4 acc[4][4] = {};

  STAGE(0, 0);
  for (int kt = 0; kt < NT; ++kt) {
    if (kt + 1 < NT) {
      STAGE((kt + 1) * 64, (kt + 1) & 1);
      asm volatile("s_waitcnt vmcnt(8)" ::: "memory");   // 8 loads of tile kt+1 remain
    } else {
      asm volatile("s_waitcnt vmcnt(0)" ::: "memory");
    }
    __builtin_amdgcn_s_barrier();
    const char* As_ = smem + (kt & 1) * 32768;
    const char* Bs_ = As_ + 16384;
    bf16x8 a[4][2], b[4][2];
    #pragma unroll
    for (int m = 0; m < 4; ++m)
      #pragma unroll
      for (int ks = 0; ks < 2; ++ks) {
        int row = wr * 64 + m * 16 + col;
        a[m][ks] = *(const bf16x8*)(As_ + row * 128 + (((ks * 4 + kq) ^ (row & 7)) << 4));
      }
    #pragma unroll
    for (int n = 0; n < 4; ++n)
      #pragma unroll
      for (int ks = 0; ks < 2; ++ks) {
        int rowb = wc * 64 + n * 16 + col;
        b[n][ks] = *(const bf16x8*)(Bs_ + rowb * 128 + (((ks * 4 + kq) ^ (rowb & 7)) << 4));
      }
    __builtin_amdgcn_s_setprio(1);
    #pragma unroll
    for (int m = 0; m < 4; ++m)
      #pragma unroll
      for (int n = 0; n < 4; ++n)
        #pragma unroll
        for (int ks = 0; ks < 2; ++ks)
          acc[m][n] = __builtin_amdgcn_mfma_f32_16x16x32_bf16(a[m][ks], b[n][ks],
                                                              acc[m][n], 0, 0, 0);
    __builtin_amdgcn_s_setprio(0);
    __builtin_amdgcn_s_barrier();
  }

  #pragma unroll
  for (int m = 0; m < 4; ++m)
    #pragma unroll
    for (int n = 0; n < 4; ++n) {
      int cc = bcol0 + wc * 64 + n * 16 + col;
      float bv = bias ? bias[cc] : 0.0f;
      #pragma unroll
      for (int i = 0; i < 4; ++i) {
        int rr = arow0 + wr * 64 + m * 16 + kq * 4 + i;
        C[(size_t)rr * ldc + cc] = acc[m][n][i] + bv;
      }
    }
}

// ---------------- Flash attention v4: 4 waves, dbuf gload_lds, counted vmcnt --
__global__ __launch_bounds__(256, 4) void attn_fwd4(const u16* __restrict__ Q,
                                                    const u16* __restrict__ K,
                                                    const u16* __restrict__ V,  // [BH][64][T]
                                                    u16* __restrict__ O) {      // [B*T][1024]
  __shared__ __align__(16) char smem[32768];  // 2 x (K 8KB + V 8KB); epilogue overlays

  const int bh = blockIdx.x;                  // XCD = bh&7 -> 4 heads per XCD L2
  const int s_ = blockIdx.y;                  // 0..15
  const int qc = (s_ & 1) ? ((s_ - 1) >> 1) : (15 - (s_ >> 1));  // 15,0,14,1,...
  const int q0 = qc * 128;
  const int b = bh >> 4, h = bh & 15;
  const int tid = threadIdx.x;
  const int wid = tid >> 6, lane = tid & 63;
  const int l31 = lane & 31, hi = lane >> 5;
  const int wq0 = q0 + wid * 32;
  const int qrow = wq0 + l31;
  const int nkt = (q0 + 128) >> 6;            // 2*(qc+1) tiles

  bf16x8 qa[4];
  const u16* qbase = Q + ((size_t)bh * T_SEQ + qrow) * 64 + hi * 8;
  #pragma unroll
  for (int dk = 0; dk < 4; ++dk)
    qa[dk] = *(const bf16x8*)(qbase + dk * 16);

  const u16* kb = K + (size_t)bh * T_SEQ * 64;
  const u16* vb = V + (size_t)bh * 64 * T_SEQ;

  auto STAGE = [&](int kv0, int bsel) {
    char* dstK = smem + bsel * 16384;
    char* dstV = dstK + 8192;
    #pragma unroll
    for (int i = 0; i < 2; ++i) {
      int idx = i * 256 + tid;
      int r = idx >> 3, c = idx & 7;
      int cs = (c ^ (r & 7)) << 3;
      gload16(kb + (size_t)(kv0 + r) * 64 + cs, dstK + idx * 16);
      gload16(vb + (size_t)r * T_SEQ + kv0 + cs, dstV + idx * 16);
    }
  };

  float M = -1e30f, L = 0.f;
  f32x16 ot0 = {}, ot1 = {};

  STAGE(0, 0);

  for (int kt = 0; kt < nkt; ++kt) {
    const int kv0 = kt << 6;
    const int cur = kt & 1;
    if (kt + 1 < nkt) {
      STAGE((kt + 1) << 6, cur ^ 1);
      asm volatile("s_waitcnt vmcnt(4)" ::: "memory");
    } else {
      asm volatile("s_waitcnt vmcnt(0)" ::: "memory");
    }
    __builtin_amdgcn_s_barrier();

    if (kv0 <= wq0 + 31) {
      const char* Ks = smem + cur * 16384;
      const char* Vs = Ks + 8192;

      f32x16 st0 = {}, st1 = {};
      __builtin_amdgcn_s_setprio(1);
      #pragma unroll
      for (int dk = 0; dk < 4; ++dk) {
        int ch = dk * 2 + hi;
        bf16x8 ka0 = *(const bf16x8*)(Ks + l31 * 128 + (((ch ^ (l31 & 7))) << 4));
        bf16x8 ka1 = *(const bf16x8*)(Ks + (l31 + 32) * 128 + ((ch ^ (l31 & 7)) << 4));
        st0 = __builtin_amdgcn_mfma_f32_32x32x16_bf16(ka0, qa[dk], st0, 0, 0, 0);
        st1 = __builtin_amdgcn_mfma_f32_32x32x16_bf16(ka1, qa[dk], st1, 0, 0, 0);
      }
      __builtin_amdgcn_s_setprio(0);

      if (kv0 + 63 > wq0) {
        #pragma unroll
        for (int r = 0; r < 16; ++r) {
          int kl = (r & 3) + 8 * (r >> 2) + 4 * hi;
          if (kv0 + kl > qrow)      st0[r] = -1e30f;
          if (kv0 + 32 + kl > qrow) st1[r] = -1e30f;
        }
      }

      float t0 = fmaxf(st0[0], st1[0]), t1 = fmaxf(st0[1], st1[1]);
      float t2 = fmaxf(st0[2], st1[2]), t3 = fmaxf(st0[3], st1[3]);
      #pragma unroll
      for (int r = 4; r < 16; r += 4) {
        t0 = fmaxf(t0, fmaxf(st0[r],     st1[r]));
        t1 = fmaxf(t1, fmaxf(st0[r + 1], st1[r + 1]));
        t2 = fmaxf(t2, fmaxf(st0[r + 2], st1[r + 2]));
        t3 = fmaxf(t3, fmaxf(st0[r + 3], st1[r + 3]));
      }
      float mx = fmaxf(fmaxf(t0, t1), fmaxf(t2, t3));
      mx = fmaxf(mx, __shfl_xor(mx, 32, 64));
      float Mn = fmaxf(M, mx);
      float corr = exp2f(M - Mn);
      M = Mn;

      float s0 = 0.f, s1 = 0.f, s2 = 0.f, s3 = 0.f;
      #pragma unroll
      for (int r = 0; r < 16; r += 4) {
        st0[r]     = exp2f(st0[r]     - M); st1[r]     = exp2f(st1[r]     - M);
        st0[r + 1] = exp2f(st0[r + 1] - M); st1[r + 1] = exp2f(st1[r + 1] - M);
        st0[r + 2] = exp2f(st0[r + 2] - M); st1[r + 2] = exp2f(st1[r + 2] - M);
        st0[r + 3] = exp2f(st0[r + 3] - M); st1[r + 3] = exp2f(st1[r + 3] - M);
        s0 += st0[r]     + st1[r];
        s1 += st0[r + 1] + st1[r + 1];
        s2 += st0[r + 2] + st1[r + 2];
        s3 += st0[r + 3] + st1[r + 3];
      }
      float sum = (s0 + s1) + (s2 + s3);
      sum += __shfl_xor(sum, 32, 64);
      L = L * corr + sum;
      ot0 *= corr;
      ot1 *= corr;

      int x0 = cvtpk(st0[0], st0[1]),   y0 = cvtpk(st0[4], st0[5]);
      int x1 = cvtpk(st0[2], st0[3]),   y1 = cvtpk(st0[6], st0[7]);
      int x2 = cvtpk(st0[8], st0[9]),   y2 = cvtpk(st0[12], st0[13]);
      int x3 = cvtpk(st0[10], st0[11]), y3 = cvtpk(st0[14], st0[15]);
      asm("v_permlane32_swap_b32 %0, %1" : "+v"(x0), "+v"(y0));
      asm("v_permlane32_swap_b32 %0, %1" : "+v"(x1), "+v"(y1));
      asm("v_permlane32_swap_b32 %0, %1" : "+v"(x2), "+v"(y2));
      asm("v_permlane32_swap_b32 %0, %1" : "+v"(x3), "+v"(y3));
      int z0 = cvtpk(st1[0], st1[1]),   w0 = cvtpk(st1[4], st1[5]);
      int z1 = cvtpk(st1[2], st1[3]),   w1 = cvtpk(st1[6], st1[7]);
      int z2 = cvtpk(st1[8], st1[9]),   w2 = cvtpk(st1[12], st1[13]);
      int z3 = cvtpk(st1[10], st1[11]), w3 = cvtpk(st1[14], st1[15]);
      asm("v_permlane32_swap_b32 %0, %1" : "+v"(z0), "+v"(w0));
      asm("v_permlane32_swap_b32 %0, %1" : "+v"(z1), "+v"(w1));
      asm("v_permlane32_swap_b32 %0, %1" : "+v"(z2), "+v"(w2));
      asm("v_permlane32_swap_b32 %0, %1" : "+v"(z3), "+v"(w3));
      bf16x8 pb[4];
      pb[0] = mkfrag(x0, x1, y0, y1);
      pb[1] = mkfrag(x2, x3, y2, y3);
      pb[2] = mkfrag(z0, z1, w0, w1);
      pb[3] = mkfrag(z2, z3, w2, w3);

      __builtin_amdgcn_s_setprio(1);
      #pragma unroll
      for (int ks = 0; ks < 4; ++ks) {
        int ch = ks * 2 + hi;
        bf16x8 va0 = *(const bf16x8*)(Vs + l31 * 128 + ((ch ^ (l31 & 7)) << 4));
        bf16x8 va1 = *(const bf16x8*)(Vs + (l31 + 32) * 128 + ((ch ^ (l31 & 7)) << 4));
        ot0 = __builtin_amdgcn_mfma_f32_32x32x16_bf16(va0, pb[ks], ot0, 0, 0, 0);
        ot1 = __builtin_amdgcn_mfma_f32_32x32x16_bf16(va1, pb[ks], ot1, 0, 0, 0);
      }
      __builtin_amdgcn_s_setprio(0);
    }

    asm volatile("s_waitcnt lgkmcnt(0)" ::: "memory");
    __builtin_amdgcn_s_barrier();
  }

  char* ep = smem + wid * 4608;
  float invL = 1.0f / L;
  #pragma unroll
  for (int r = 0; r < 16; r += 2) {
    int d0_ = (r & 3) + 8 * (r >> 2) + 4 * hi;
    int wA = cvtpk(ot0[r] * invL, ot0[r + 1] * invL);
    *(int*)(ep + l31 * 144 + d0_ * 2) = wA;
    int wB = cvtpk(ot1[r] * invL, ot1[r + 1] * invL);
    *(int*)(ep + l31 * 144 + (32 + d0_) * 2) = wB;
  }
  asm volatile("s_waitcnt lgkmcnt(0)" ::: "memory");
  #pragma unroll
  for (int pass = 0; pass < 4; ++pass) {
    int qr = pass * 8 + (lane >> 3);
    bf16x8 val = *(const bf16x8*)(ep + qr * 144 + (lane & 7) * 16);
    int t = wq0 + qr;
    *(bf16x8*)(O + ((size_t)(b * T_SEQ + t)) * 1024 + h * 64 + (lane & 7) * 8) = val;
  }
}

// ---------------- host launch ----------------
extern "C" void kernel_launch(void* const* d_in, const int* in_sizes, int n_in,
                              void* d_out, int out_size, void* d_ws, size_t ws_size,
                              hipStream_t stream) {
  (void)in_sizes; (void)n_in; (void)out_size; (void)ws_size;
  const float* x  = (const float*)d_in[0];
  const float* Wq = (const float*)d_in[1];
  const float* Wk = (const float*)d_in[2];
  const float* Wv = (const float*)d_in[3];
  const float* Wo = (const float*)d_in[4];
  const float* bo = (const float*)d_in[5];
  float* out = (float*)d_out;

  char* ws = (char*)d_ws;
  u16*   xb   = (u16*)(ws);                         //  8 MB
  u16*   Wqkv = (u16*)(ws + (size_t)( 8u << 20));   //  6 MB  [3072][1024] bf16
  u16*   Wot  = (u16*)(ws + (size_t)(14u << 20));   //  2 MB
  u16*   Qr   = (u16*)(ws + (size_t)(16u << 20));   //  8 MB  [BH][T][64]
  u16*   Kr   = (u16*)(ws + (size_t)(24u << 20));   //  8 MB
  u16*   Vt   = (u16*)(ws + (size_t)(32u << 20));   //  8 MB  [BH][64][T]
  u16*   Ob   = (u16*)(ws + (size_t)(40u << 20));   //  8 MB  [4096][1024]
  float* cosT = (float*)(ws + (size_t)(48u << 20)); // 256 KB
  float* sinT = (float*)(ws + (size_t)(48u << 20) + (1u << 18));

  cvt4<<<dim3(MROWS * CDIM / 4 / 256), dim3(256), 0, stream>>>(
      (const float4*)x, (u16x4*)xb, MROWS * CDIM / 4);
  w_trans4<<<dim3(16, 16, 4), dim3(256), 0, stream>>>(Wq, Wk, Wv, Wo, Wqkv, Wot);
  rope_tab<<<dim3(T_SEQ * 32 / 256), dim3(256), 0, stream>>>(cosT, sinT);

  // fused QKV projection + RoPE + head layout (256x192 tile, 8 waves, 256 blocks)
  gemm_qkv256<<<dim3(256), dim3(512), 0, stream>>>(xb, Wqkv, cosT, sinT, Qr, Kr, Vt);

  // attention (dbuf LDS, counted vmcnt)
  attn_fwd4<<<dim3(32, 16), dim3(256), 0, stream>>>(Qr, Kr, Vt, Ob);

  // output projection + bias -> f32 out
  gemm_bt<<<dim3(256), dim3(256), 0, stream>>>(Ob, Wot, out, bo, CDIM, CDIM);
}